// Round 6
// baseline (618.420 us; speedup 1.0000x reference)
//
#include <hip/hip_runtime.h>

// ---------------------------------------------------------------------------
// Round 6: full-GPU utilization.
//  - 256 blocks x 8 batch (was 128 x 16): all 256 CUs busy.
//  - quad-split elementwise: rows 8-15 of every 16x16 C-tile are garbage;
//    shfl_xor(32) redistributes valid gates so each lane does 2 cells not 4.
//  - merged-rcp cell math: 5 exp + 3 rcp (+2 clamps) per cell, was 5+5.
// Encoder: wavefront pipeline (wave l = layer l). Decoder: col-sliced waves
// with precomputed recurrent partials, proj fused into interval A.
// ---------------------------------------------------------------------------

#define S_LEN 120
#define BATCH 2048
#define NIN   6
#define H     64
#define NL    4
#define TLEN  120
#define BB    8            // batch rows per block (valid rows of the M=16 tile)

#define HPAD 72            // row stride in halves (144 B)

#define FRAGS_HALF 60      // col-sliced: 12 (layer0) + 3*16
#define PACK_H8    (2 * FRAGS_HALF * 4 * 64)
#define PROJ_H8    (2 * 64)
#define NPACK      ((PACK_H8 + PROJ_H8) * 8)   // 246784 fp16 elements
#define EPACK_EL   (256 * 64 * 8)              // encoder pipeline pack
#define NTOT       (NPACK + EPACK_EL)

#define PERM(kk) ((((kk) & 3) << 4) | ((kk) >> 2))   // pi^-1
#define PI(c)    ((((c) & 15) << 2) | ((c) >> 4))    // pi

typedef _Float16 h8    __attribute__((ext_vector_type(8)));
typedef _Float16 h4    __attribute__((ext_vector_type(4)));
typedef float    f32x4 __attribute__((ext_vector_type(4)));

// ---------------------------------------------------------------------------
// Weight pack (identical to round 5 — independent of batch grouping).
// ---------------------------------------------------------------------------
__global__ void prep_weights(const float* __restrict__ eWih0,
                             const float* __restrict__ eWih,
                             const float* __restrict__ eWhh,
                             const float* __restrict__ dWih0,
                             const float* __restrict__ dWih,
                             const float* __restrict__ dWhh,
                             const float* __restrict__ linW,
                             _Float16* __restrict__ wq) {
  int idx = blockIdx.x * blockDim.x + threadIdx.x;
  if (idx >= NTOT) return;

  if (idx >= NPACK) {                      // ---- encoder pipeline pack ----
    int p    = idx - NPACK;
    int j    = p & 7;
    int lane = (p >> 3) & 63;
    int fe   = p >> 9;
    int kt   = fe & 3, nt = (fe >> 2) & 15, l = fe >> 6;
    int g    = nt * 16 + (lane & 15);
    int koff = ((lane >> 4) << 3) + j;
    float v = 0.0f;
    if (l == 0) {
      if (kt == 0)      v = (koff < NIN) ? eWih0[g * NIN + koff] : 0.0f;
      else if (kt == 1) v = 0.0f;
      else { int kk = (kt - 2) * 32 + koff; v = eWhh[g * H + PERM(kk)]; }
    } else {
      if (kt < 2) { int kk = kt * 32 + koff;
                    v = eWih[((l - 1) * 256 + g) * H + PERM(kk)]; }
      else        { int kk = (kt - 2) * 32 + koff;
                    v = eWhh[(l * 256 + g) * H + PERM(kk)]; }
    }
    wq[idx] = (_Float16)v;
    return;
  }

  if (idx >= PACK_H8 * 8) {                // ---- linW A-layout frags ----
    int p    = idx - PACK_H8 * 8;
    int j    = p & 7;
    int lane = (p >> 3) & 63;
    int fr   = p >> 9;
    int m    = lane & 15;
    int k    = fr * 32 + ((lane >> 4) << 3) + j;
    wq[idx] = (_Float16)((m < NIN) ? linW[m * H + k] : 0.0f);
    return;
  }

  // ---- col-sliced pack (decoder uses dec half) ----
  const int j    = idx & 7;
  const int lane = (idx >> 3) & 63;
  const int wv   = (idx >> 9) & 3;
  const int fh   = idx >> 11;
  const int f    = fh % FRAGS_HALF;
  const int half = fh / FRAGS_HALF;
  const float* Wi0 = half ? dWih0 : eWih0;
  const float* Wi  = half ? dWih  : eWih;
  const float* Wh  = half ? dWhh  : eWhh;
  int l, q, kt;
  if (f < 12) { l = 0; q = f / 3; kt = f % 3; }
  else        { int ff = f - 12; l = 1 + ff / 16; ff %= 16; q = ff / 4; kt = ff % 4; }
  const int g    = q * 64 + wv * 16 + (lane & 15);
  const int k_in = ((lane >> 4) << 3) + j;
  float v;
  if (l == 0) {
    if (kt == 0) v = (k_in < NIN) ? Wi0[g * NIN + k_in] : 0.0f;
    else         v = Wh[g * H + (kt - 1) * 32 + k_in];
  } else {
    if (kt < 2) v = Wi[((l - 1) * 256 + g) * H + kt * 32 + k_in];
    else        v = Wh[(l * 256 + g) * H + (kt - 2) * 32 + k_in];
  }
  wq[idx] = (_Float16)v;
}

// ---------------------------------------------------------------------------
__device__ __forceinline__ float rcpf(float x) { return __builtin_amdgcn_rcpf(x); }
__device__ __forceinline__ f32x4 mf(h8 a, h8 b, f32x4 c) {
  return __builtin_amdgcn_mfma_f32_16x16x32_f16(a, b, c, 0, 0, 0);
}
#define SPLAT(v) ((f32x4){(v), (v), (v), (v)})

// merged-rcp LSTM cell: 5 exp + 3 rcp; clamps keep e^(2x) finite.
__device__ __forceinline__ float ew_one(float gi, float gf, float gg, float go,
                                        float& c) {
  gg = fminf(fmaxf(gg, -20.0f), 20.0f);
  float eni = __expf(-gi);
  float e2g = __expf(2.0f * gg);
  float enf = __expf(-gf);
  float eno = __expf(-go);
  c = c * rcpf(1.0f + enf) + (e2g - 1.0f) * rcpf((1.0f + eni) * (e2g + 1.0f));
  float cc = fminf(fmaxf(c, -20.0f), 20.0f);
  float e2c = __expf(2.0f * cc);
  return (e2c - 1.0f) * rcpf((1.0f + eno) * (e2c + 1.0f));
}

// decoder: redistribute gates (quads 2,3 take partner's r=2,3), 2 cells/lane
__device__ __forceinline__ void ew_store2(f32x4 g0, f32x4 g1, f32x4 g2, f32x4 g3,
                                          float2& c2, _Float16* outbuf,
                                          int rowA, bool hi, int colOff) {
  float pi0 = __shfl_xor(g0[2], 32), pi1 = __shfl_xor(g0[3], 32);
  float pf0 = __shfl_xor(g1[2], 32), pf1 = __shfl_xor(g1[3], 32);
  float pg0 = __shfl_xor(g2[2], 32), pg1 = __shfl_xor(g2[3], 32);
  float po0 = __shfl_xor(g3[2], 32), po1 = __shfl_xor(g3[3], 32);
  float i0 = hi ? pi0 : g0[0], i1 = hi ? pi1 : g0[1];
  float f0 = hi ? pf0 : g1[0], f1 = hi ? pf1 : g1[1];
  float q0 = hi ? pg0 : g2[0], q1 = hi ? pg1 : g2[1];
  float o0 = hi ? po0 : g3[0], o1 = hi ? po1 : g3[1];
  float h0v = ew_one(i0, f0, q0, o0, c2.x);
  float h1v = ew_one(i1, f1, q1, o1, c2.y);
  outbuf[rowA * HPAD + colOff]       = (_Float16)h0v;
  outbuf[(rowA + 1) * HPAD + colOff] = (_Float16)h1v;
}

__device__ __forceinline__ void fireH(const h8 (&w)[16], h8 ai0, h8 ai1,
                                      const f32x4 (&ac)[4], float2& c2,
                                      _Float16* outbuf, int rowA, bool hi,
                                      int colOff) {
  f32x4 g0 = mf(ai1, w[1],  mf(ai0, w[0],  ac[0]));
  f32x4 g1 = mf(ai1, w[5],  mf(ai0, w[4],  ac[1]));
  f32x4 g2 = mf(ai1, w[9],  mf(ai0, w[8],  ac[2]));
  f32x4 g3 = mf(ai1, w[13], mf(ai0, w[12], ac[3]));
  ew_store2(g0, g1, g2, g3, c2, outbuf, rowA, hi, colOff);
}
__device__ __forceinline__ void precH(const h8 (&w)[16], h8 ar0, h8 ar1,
                                      f32x4 b, f32x4 (&ac)[4]) {
  ac[0] = mf(ar1, w[3],  mf(ar0, w[2],  SPLAT(b[0])));
  ac[1] = mf(ar1, w[7],  mf(ar0, w[6],  SPLAT(b[1])));
  ac[2] = mf(ar1, w[11], mf(ar0, w[10], SPLAT(b[2])));
  ac[3] = mf(ar1, w[15], mf(ar0, w[14], SPLAT(b[3])));
}
__device__ __forceinline__ void fire0(const h8 (&w)[12], h8 ax,
                                      const f32x4 (&ac)[4], float2& c2,
                                      _Float16* outbuf, int rowA, bool hi,
                                      int colOff) {
  f32x4 g0 = mf(ax, w[0], ac[0]);
  f32x4 g1 = mf(ax, w[3], ac[1]);
  f32x4 g2 = mf(ax, w[6], ac[2]);
  f32x4 g3 = mf(ax, w[9], ac[3]);
  ew_store2(g0, g1, g2, g3, c2, outbuf, rowA, hi, colOff);
}
__device__ __forceinline__ void prec0(const h8 (&w)[12], h8 ar0, h8 ar1,
                                      f32x4 b, f32x4 (&ac)[4]) {
  ac[0] = mf(ar1, w[2],  mf(ar0, w[1],  SPLAT(b[0])));
  ac[1] = mf(ar1, w[5],  mf(ar0, w[4],  SPLAT(b[1])));
  ac[2] = mf(ar1, w[8],  mf(ar0, w[7],  SPLAT(b[2])));
  ac[3] = mf(ar1, w[11], mf(ar0, w[10], SPLAT(b[3])));
}
__device__ __forceinline__ void readA(const _Float16* buf, int r16, int quad,
                                      h8& a0, h8& a1) {
  a0 = *(const h8*)(buf + r16 * HPAD + quad * 8);
  a1 = *(const h8*)(buf + r16 * HPAD + 32 + quad * 8);
}

// ---------------------------------------------------------------------------
__global__ void __launch_bounds__(256, 1)
lstm_main(const float* __restrict__ X,
          const float* __restrict__ encb,
          const float* __restrict__ decb,
          const float* __restrict__ linb,
          const h8* __restrict__ WQ,
          float* __restrict__ out) {
  __shared__ _Float16 Hb[NL][2][16][HPAD];   // 18432 B (rows 8-15 stay zero)
  __shared__ _Float16 Xb[2][16][HPAD];       //  4608 B (rows 8-15 / cols>=6 zero)
  __shared__ float    Cx[NL][BB][68];        //  8704 B (c hand-off)

  const int tid   = threadIdx.x;
  const int wv    = tid >> 6;
  const int lane  = tid & 63;
  const int quad  = lane >> 4;
  const int r16   = lane & 15;
  const bool hi   = quad >= 2;
  const int rowA  = hi ? (quad - 2) * 4 + 2 : quad * 4;  // this lane's 2 rows
  const int bbase = blockIdx.x * BB;

  // zero Hb + Xb
  {
    float* p = (float*)&Hb[0][0][0][0];
    for (int i = tid; i < (int)(NL * 2 * 16 * HPAD / 2); i += 256) p[i] = 0.0f;
    float* px = (float*)&Xb[0][0][0];
    for (int i = tid; i < (int)(2 * 16 * HPAD / 2); i += 256) px[i] = 0.0f;
  }
  if (tid < BB * NIN) {
    const int m = tid / NIN, ii = tid - m * NIN;
    Xb[0][m][ii] = (_Float16)X[((size_t)0 * BATCH + bbase + m) * NIN + ii];
  }

  // ======================= ENCODER: wavefront pipeline =====================
  h8 we[16][4];
  #pragma unroll
  for (int nt = 0; nt < 16; nt++)
    #pragma unroll
    for (int kt = 0; kt < 4; kt++)
      we[nt][kt] = WQ[(PACK_H8 + PROJ_H8) + ((wv * 64 + nt * 4 + kt) * 64 + lane)];

  float ben[16];
  #pragma unroll
  for (int nt = 0; nt < 16; nt++) ben[nt] = encb[wv * 256 + nt * 16 + r16];

  float2 ce2[4];                      // c for (rowA,rowA+1) x 4 col-tiles
  #pragma unroll
  for (int ct = 0; ct < 4; ct++) ce2[ct] = make_float2(0.f, 0.f);

  __syncthreads();

  #pragma unroll 1
  for (int i = 0; i < S_LEN + NL - 1; i++) {     // 123 intervals
    const int p = i & 1;
    const bool active = (i >= wv) && (i - wv < S_LEN);
    if (active) {
      const _Float16* inb = (wv == 0) ? &Xb[p][0][0] : &Hb[wv - 1][p ^ 1][0][0];
      const _Float16* rcb = &Hb[wv][p ^ 1][0][0];
      h8 ai0 = *(const h8*)(inb + r16 * HPAD + quad * 8);
      h8 ai1 = *(const h8*)(inb + r16 * HPAD + 32 + quad * 8);
      h8 ar0 = *(const h8*)(rcb + r16 * HPAD + quad * 8);
      h8 ar1 = *(const h8*)(rcb + r16 * HPAD + 32 + quad * 8);

      float pfv = 0.f; int pm = 0, pix = 0;
      const bool doPf = (wv == 0) && (lane < BB * NIN) && (i + 1 < S_LEN);
      if (doPf) {
        pm = lane / NIN; pix = lane - pm * NIN;
        pfv = X[((size_t)(i + 1) * BATCH + bbase + pm) * NIN + pix];
      }

      f32x4 acc[16];
      #pragma unroll
      for (int nt = 0; nt < 16; nt++) {
        f32x4 a = SPLAT(ben[nt]);
        a = mf(ai0, we[nt][0], a);
        a = mf(ai1, we[nt][1], a);
        a = mf(ar0, we[nt][2], a);
        a = mf(ar1, we[nt][3], a);
        acc[nt] = a;
      }

      // redistribute: each lane keeps gates of its 2 valid rows
      float va[16][2];
      #pragma unroll
      for (int nt = 0; nt < 16; nt++) {
        float a2 = __shfl_xor(acc[nt][2], 32);
        float a3 = __shfl_xor(acc[nt][3], 32);
        va[nt][0] = hi ? a2 : acc[nt][0];
        va[nt][1] = hi ? a3 : acc[nt][1];
      }

      _Float16* wb = &Hb[wv][p][0][0];
      #pragma unroll
      for (int s = 0; s < 2; s++) {
        h4 hv;
        #pragma unroll
        for (int ct = 0; ct < 4; ct++) {
          float& cref = s ? ce2[ct].y : ce2[ct].x;
          hv[ct] = (_Float16)ew_one(va[ct][s], va[4 + ct][s],
                                    va[8 + ct][s], va[12 + ct][s], cref);
        }
        *(h4*)(wb + (rowA + s) * HPAD + 4 * r16) = hv;   // permuted write
      }

      if (doPf) Xb[p ^ 1][pm][pix] = (_Float16)pfv;
    }
    __syncthreads();
  }

  // ===================== transition: encoder -> decoder ====================
  #pragma unroll
  for (int ct = 0; ct < 4; ct++) {
    Cx[wv][rowA][ct * 16 + r16]     = ce2[ct].x;
    Cx[wv][rowA + 1][ct * 16 + r16] = ce2[ct].y;
  }

  // unpermute final h (8 valid rows) into Hb[l][1] plain layout
  float hreg[8];
  #pragma unroll
  for (int u = 0; u < 8; u++) {
    int i2 = tid + u * 256;
    int l = i2 >> 9, m = (i2 >> 6) & 7, c = i2 & 63;
    hreg[u] = (float)Hb[l][(l + 1) & 1][m][PI(c)];
  }
  __syncthreads();
  #pragma unroll
  for (int u = 0; u < 8; u++) {
    int i2 = tid + u * 256;
    int l = i2 >> 9, m = (i2 >> 6) & 7, c = i2 & 63;
    Hb[l][1][m][c] = (_Float16)hreg[u];
  }
  __syncthreads();

  // decoder c-state: this lane's 2 rows of its col (wv*16 + r16)
  const int cw = wv * 16 + r16;
  float2 cs0 = make_float2(Cx[0][rowA][cw], Cx[0][rowA + 1][cw]);
  float2 cs1 = make_float2(Cx[1][rowA][cw], Cx[1][rowA + 1][cw]);
  float2 cs2 = make_float2(Cx[2][rowA][cw], Cx[2][rowA + 1][cw]);
  float2 cs3 = make_float2(Cx[3][rowA][cw], Cx[3][rowA + 1][cw]);

  // decoder weights + biases
  h8 w0[12], w1[16], w2[16], w3[16];
  #pragma unroll
  for (int f = 0; f < 12; f++) w0[f] = WQ[((FRAGS_HALF + f)      * 4 + wv) * 64 + lane];
  #pragma unroll
  for (int f = 0; f < 16; f++) w1[f] = WQ[((FRAGS_HALF + 12 + f) * 4 + wv) * 64 + lane];
  #pragma unroll
  for (int f = 0; f < 16; f++) w2[f] = WQ[((FRAGS_HALF + 28 + f) * 4 + wv) * 64 + lane];
  #pragma unroll
  for (int f = 0; f < 16; f++) w3[f] = WQ[((FRAGS_HALF + 44 + f) * 4 + wv) * 64 + lane];

  f32x4 b0, b1, b2, b3;
  #pragma unroll
  for (int q = 0; q < 4; q++) {
    b0[q] = decb[0 * 256 + q * 64 + wv * 16 + r16];
    b1[q] = decb[1 * 256 + q * 64 + wv * 16 + r16];
    b2[q] = decb[2 * 256 + q * 64 + wv * 16 + r16];
    b3[q] = decb[3 * 256 + q * 64 + wv * 16 + r16];
  }

  h8 lwA0 = WQ[PACK_H8 + lane];
  h8 lwA1 = WQ[PACK_H8 + 64 + lane];
  f32x4 lbq;
  #pragma unroll
  for (int r = 0; r < 4; r++)
    lbq[r] = (quad * 4 + r < NIN) ? linb[quad * 4 + r] : 0.0f;

  f32x4 ac0[4], ac1[4], ac2[4], ac3[4];
  {
    h8 s0, s1;
    readA(&Hb[0][1][0][0], r16, quad, s0, s1); prec0(w0, s0, s1, b0, ac0);
    readA(&Hb[1][1][0][0], r16, quad, s0, s1); precH(w1, s0, s1, b1, ac1);
    readA(&Hb[2][1][0][0], r16, quad, s0, s1); precH(w2, s0, s1, b2, ac2);
  }
  __syncthreads();

  // ============================== DECODER ================================
  #pragma unroll 1
  for (int t = 0; t < TLEN; t++) {
    const int cur = t & 1, prv = cur ^ 1;
    // ---- interval A: proj(h3[t-1]) + layer-0 fire + acc3 precompute ----
    {
      h8 ar0, ar1;
      readA(&Hb[3][prv][0][0], r16, quad, ar0, ar1);
      h8 ax;
      if (t == 0) {
        ax = *(const h8*)(&Xb[1][0][0] + r16 * HPAD + quad * 8);  // x[119]
      } else {
        f32x4 ap = lbq;
        ap = mf(lwA0, ar0, ap);     // A = linW (m=feature), B = h3 (n=batch)
        ap = mf(lwA1, ar1, ap);
        if (wv == 0 && r16 < BB) {
          #pragma unroll
          for (int r = 0; r < 4; r++) {
            const int fm = quad * 4 + r;
            if (fm < NIN)
              out[((size_t)(t - 1) * BATCH + bbase + r16) * NIN + fm] = ap[r];
          }
        }
        // transpose (feature,batch)->(batch,feature); batch = lane&15
        float x0 = __shfl(ap[0], r16);
        float x1 = __shfl(ap[1], r16);
        float x2 = __shfl(ap[2], r16);
        float x3 = __shfl(ap[3], r16);
        float x4 = __shfl(ap[0], 16 + r16);
        float x5 = __shfl(ap[1], 16 + r16);
        h8 xa = {};
        xa[0] = (_Float16)x0; xa[1] = (_Float16)x1; xa[2] = (_Float16)x2;
        xa[3] = (_Float16)x3; xa[4] = (_Float16)x4; xa[5] = (_Float16)x5;
        h8 zz = {};
        ax = (quad == 0) ? xa : zz;
      }
      precH(w3, ar0, ar1, b3, ac3);
      fire0(w0, ax, ac0, cs0, &Hb[0][cur][0][0], rowA, hi, cw);
      __syncthreads();
    }
    // ---- interval B ----
    {
      h8 ai0, ai1;
      readA(&Hb[0][cur][0][0], r16, quad, ai0, ai1);
      fireH(w1, ai0, ai1, ac1, cs1, &Hb[1][cur][0][0], rowA, hi, cw);
      prec0(w0, ai0, ai1, b0, ac0);
      __syncthreads();
    }
    // ---- interval C ----
    {
      h8 ai0, ai1;
      readA(&Hb[1][cur][0][0], r16, quad, ai0, ai1);
      fireH(w2, ai0, ai1, ac2, cs2, &Hb[2][cur][0][0], rowA, hi, cw);
      precH(w1, ai0, ai1, b1, ac1);
      __syncthreads();
    }
    // ---- interval D ----
    {
      h8 ai0, ai1;
      readA(&Hb[2][cur][0][0], r16, quad, ai0, ai1);
      fireH(w3, ai0, ai1, ac3, cs3, &Hb[3][cur][0][0], rowA, hi, cw);
      precH(w2, ai0, ai1, b2, ac2);
      __syncthreads();
    }
  }

  // epilogue: out[TLEN-1] from h3 (parity 1)
  if (wv == 0) {
    h8 ar0, ar1;
    readA(&Hb[3][1][0][0], r16, quad, ar0, ar1);
    f32x4 ap = lbq;
    ap = mf(lwA0, ar0, ap);
    ap = mf(lwA1, ar1, ap);
    if (r16 < BB) {
      #pragma unroll
      for (int r = 0; r < 4; r++) {
        const int fm = quad * 4 + r;
        if (fm < NIN)
          out[((size_t)(TLEN - 1) * BATCH + bbase + r16) * NIN + fm] = ap[r];
      }
    }
  }
}

// ---------------------------------------------------------------------------
extern "C" void kernel_launch(void* const* d_in, const int* in_sizes, int n_in,
                              void* d_out, int out_size, void* d_ws, size_t ws_size,
                              hipStream_t stream) {
  const float* X     = (const float*)d_in[0];
  const float* eWih0 = (const float*)d_in[1];
  const float* eWih  = (const float*)d_in[2];
  const float* eWhh  = (const float*)d_in[3];
  const float* eb    = (const float*)d_in[4];
  const float* dWih0 = (const float*)d_in[5];
  const float* dWih  = (const float*)d_in[6];
  const float* dWhh  = (const float*)d_in[7];
  const float* db    = (const float*)d_in[8];
  const float* lW    = (const float*)d_in[9];
  const float* lb    = (const float*)d_in[10];

  _Float16* wq = (_Float16*)d_ws;

  prep_weights<<<(NTOT + 255) / 256, 256, 0, stream>>>(
      eWih0, eWih, eWhh, dWih0, dWih, dWhh, lW, wq);

  lstm_main<<<BATCH / BB, 256, 0, stream>>>(
      X, eb, db, lb, (const h8*)wq, (float*)d_out);
}

// Round 7
// 593.392 us; speedup vs baseline: 1.0422x; 1.0422x over previous
//
#include <hip/hip_runtime.h>

// ---------------------------------------------------------------------------
// Round 7: R5 structure (BB=16, 128 blocks; encoder wavefront pipeline,
// decoder col-sliced with precomputed recurrent partials, proj fused) plus:
//  - lgkm-only barriers in steady-state loops: __syncthreads drains
//    vmcnt(0), putting global prefetch/store latency on the barrier path.
//    Replaced by "s_waitcnt lgkmcnt(0); s_barrier" (LDS ordering preserved;
//    no cross-wave consumer of global ops exists).
//  - 2-deep X prefetch: global load -> Xb ds_write crosses a full interval.
//  - merged-rcp cell math (5 exp + 3 rcp), absmax-validated in R6.
// ---------------------------------------------------------------------------

#define S_LEN 120
#define BATCH 2048
#define NIN   6
#define H     64
#define NL    4
#define TLEN  120

#define HPAD 72            // row stride in halves (144 B)

#define FRAGS_HALF 60      // col-sliced: 12 (layer0) + 3*16
#define PACK_H8    (2 * FRAGS_HALF * 4 * 64)
#define PROJ_H8    (2 * 64)
#define NPACK      ((PACK_H8 + PROJ_H8) * 8)   // 246784 fp16 elements
#define EPACK_EL   (256 * 64 * 8)              // encoder pipeline pack
#define NTOT       (NPACK + EPACK_EL)

#define PERM(kk) ((((kk) & 3) << 4) | ((kk) >> 2))   // pi^-1
#define PI(c)    ((((c) & 15) << 2) | ((c) >> 4))    // pi

typedef _Float16 h8    __attribute__((ext_vector_type(8)));
typedef _Float16 h4    __attribute__((ext_vector_type(4)));
typedef float    f32x4 __attribute__((ext_vector_type(4)));

// lgkm-only barrier: LDS ordering without the vmcnt(0) global drain.
__device__ __forceinline__ void bar_lgkm() {
  asm volatile("s_waitcnt lgkmcnt(0)\n\ts_barrier" ::: "memory");
}

// ---------------------------------------------------------------------------
// Weight pack (identical to round 5).
// ---------------------------------------------------------------------------
__global__ void prep_weights(const float* __restrict__ eWih0,
                             const float* __restrict__ eWih,
                             const float* __restrict__ eWhh,
                             const float* __restrict__ dWih0,
                             const float* __restrict__ dWih,
                             const float* __restrict__ dWhh,
                             const float* __restrict__ linW,
                             _Float16* __restrict__ wq) {
  int idx = blockIdx.x * blockDim.x + threadIdx.x;
  if (idx >= NTOT) return;

  if (idx >= NPACK) {                      // ---- encoder pipeline pack ----
    int p    = idx - NPACK;
    int j    = p & 7;
    int lane = (p >> 3) & 63;
    int fe   = p >> 9;
    int kt   = fe & 3, nt = (fe >> 2) & 15, l = fe >> 6;
    int g    = nt * 16 + (lane & 15);
    int koff = ((lane >> 4) << 3) + j;
    float v = 0.0f;
    if (l == 0) {
      if (kt == 0)      v = (koff < NIN) ? eWih0[g * NIN + koff] : 0.0f;
      else if (kt == 1) v = 0.0f;
      else { int kk = (kt - 2) * 32 + koff; v = eWhh[g * H + PERM(kk)]; }
    } else {
      if (kt < 2) { int kk = kt * 32 + koff;
                    v = eWih[((l - 1) * 256 + g) * H + PERM(kk)]; }
      else        { int kk = (kt - 2) * 32 + koff;
                    v = eWhh[(l * 256 + g) * H + PERM(kk)]; }
    }
    wq[idx] = (_Float16)v;
    return;
  }

  if (idx >= PACK_H8 * 8) {                // ---- linW A-layout frags ----
    int p    = idx - PACK_H8 * 8;
    int j    = p & 7;
    int lane = (p >> 3) & 63;
    int fr   = p >> 9;
    int m    = lane & 15;
    int k    = fr * 32 + ((lane >> 4) << 3) + j;
    wq[idx] = (_Float16)((m < NIN) ? linW[m * H + k] : 0.0f);
    return;
  }

  // ---- col-sliced pack (decoder uses dec half) ----
  const int j    = idx & 7;
  const int lane = (idx >> 3) & 63;
  const int wv   = (idx >> 9) & 3;
  const int fh   = idx >> 11;
  const int f    = fh % FRAGS_HALF;
  const int half = fh / FRAGS_HALF;
  const float* Wi0 = half ? dWih0 : eWih0;
  const float* Wi  = half ? dWih  : eWih;
  const float* Wh  = half ? dWhh  : eWhh;
  int l, q, kt;
  if (f < 12) { l = 0; q = f / 3; kt = f % 3; }
  else        { int ff = f - 12; l = 1 + ff / 16; ff %= 16; q = ff / 4; kt = ff % 4; }
  const int g    = q * 64 + wv * 16 + (lane & 15);
  const int k_in = ((lane >> 4) << 3) + j;
  float v;
  if (l == 0) {
    if (kt == 0) v = (k_in < NIN) ? Wi0[g * NIN + k_in] : 0.0f;
    else         v = Wh[g * H + (kt - 1) * 32 + k_in];
  } else {
    if (kt < 2) v = Wi[((l - 1) * 256 + g) * H + kt * 32 + k_in];
    else        v = Wh[(l * 256 + g) * H + (kt - 2) * 32 + k_in];
  }
  wq[idx] = (_Float16)v;
}

// ---------------------------------------------------------------------------
__device__ __forceinline__ float rcpf(float x) { return __builtin_amdgcn_rcpf(x); }
__device__ __forceinline__ f32x4 mf(h8 a, h8 b, f32x4 c) {
  return __builtin_amdgcn_mfma_f32_16x16x32_f16(a, b, c, 0, 0, 0);
}
#define SPLAT(v) ((f32x4){(v), (v), (v), (v)})

// merged-rcp LSTM cell: 5 exp + 3 rcp (+2 clamps); validated in round 6.
__device__ __forceinline__ float ew_one(float gi, float gf, float gg, float go,
                                        float& c) {
  gg = fminf(fmaxf(gg, -20.0f), 20.0f);
  float eni = __expf(-gi);
  float e2g = __expf(2.0f * gg);
  float enf = __expf(-gf);
  float eno = __expf(-go);
  c = c * rcpf(1.0f + enf) + (e2g - 1.0f) * rcpf((1.0f + eni) * (e2g + 1.0f));
  float cc = fminf(fmaxf(c, -20.0f), 20.0f);
  float e2c = __expf(2.0f * cc);
  return (e2c - 1.0f) * rcpf((1.0f + eno) * (e2c + 1.0f));
}

__device__ __forceinline__ void cell_ew(f32x4 g0, f32x4 g1, f32x4 g2, f32x4 g3,
                                        f32x4& c, _Float16* outbuf,
                                        int quad, int r16, int wv) {
  #pragma unroll
  for (int r = 0; r < 4; r++) {
    float cv = c[r];
    float hv = ew_one(g0[r], g1[r], g2[r], g3[r], cv);
    c[r] = cv;
    outbuf[(quad * 4 + r) * HPAD + wv * 16 + r16] = (_Float16)hv;
  }
}
__device__ __forceinline__ void fireH(const h8 (&w)[16], h8 ai0, h8 ai1,
                                      const f32x4 (&ac)[4], f32x4& c,
                                      _Float16* outbuf, int quad, int r16, int wv) {
  f32x4 g0 = mf(ai1, w[1],  mf(ai0, w[0],  ac[0]));
  f32x4 g1 = mf(ai1, w[5],  mf(ai0, w[4],  ac[1]));
  f32x4 g2 = mf(ai1, w[9],  mf(ai0, w[8],  ac[2]));
  f32x4 g3 = mf(ai1, w[13], mf(ai0, w[12], ac[3]));
  cell_ew(g0, g1, g2, g3, c, outbuf, quad, r16, wv);
}
__device__ __forceinline__ void precH(const h8 (&w)[16], h8 ar0, h8 ar1,
                                      f32x4 b, f32x4 (&ac)[4]) {
  ac[0] = mf(ar1, w[3],  mf(ar0, w[2],  SPLAT(b[0])));
  ac[1] = mf(ar1, w[7],  mf(ar0, w[6],  SPLAT(b[1])));
  ac[2] = mf(ar1, w[11], mf(ar0, w[10], SPLAT(b[2])));
  ac[3] = mf(ar1, w[15], mf(ar0, w[14], SPLAT(b[3])));
}
__device__ __forceinline__ void fire0(const h8 (&w)[12], h8 ax,
                                      const f32x4 (&ac)[4], f32x4& c,
                                      _Float16* outbuf, int quad, int r16, int wv) {
  f32x4 g0 = mf(ax, w[0], ac[0]);
  f32x4 g1 = mf(ax, w[3], ac[1]);
  f32x4 g2 = mf(ax, w[6], ac[2]);
  f32x4 g3 = mf(ax, w[9], ac[3]);
  cell_ew(g0, g1, g2, g3, c, outbuf, quad, r16, wv);
}
__device__ __forceinline__ void prec0(const h8 (&w)[12], h8 ar0, h8 ar1,
                                      f32x4 b, f32x4 (&ac)[4]) {
  ac[0] = mf(ar1, w[2],  mf(ar0, w[1],  SPLAT(b[0])));
  ac[1] = mf(ar1, w[5],  mf(ar0, w[4],  SPLAT(b[1])));
  ac[2] = mf(ar1, w[8],  mf(ar0, w[7],  SPLAT(b[2])));
  ac[3] = mf(ar1, w[11], mf(ar0, w[10], SPLAT(b[3])));
}
__device__ __forceinline__ void readA(const _Float16* buf, int r16, int quad,
                                      h8& a0, h8& a1) {
  a0 = *(const h8*)(buf + r16 * HPAD + quad * 8);
  a1 = *(const h8*)(buf + r16 * HPAD + 32 + quad * 8);
}

// ---------------------------------------------------------------------------
__global__ void __launch_bounds__(256, 1)
lstm_main(const float* __restrict__ X,
          const float* __restrict__ encb,
          const float* __restrict__ decb,
          const float* __restrict__ linb,
          const h8* __restrict__ WQ,
          float* __restrict__ out) {
  __shared__ _Float16 Hb[NL][2][16][HPAD];   // 18432 B
  __shared__ _Float16 Xb[2][16][HPAD];       //  4608 B (cols >=6 stay zero)
  __shared__ float    Cx[NL][16][68];        // 17408 B (c hand-off)

  const int tid   = threadIdx.x;
  const int wv    = tid >> 6;
  const int lane  = tid & 63;
  const int quad  = lane >> 4;
  const int r16   = lane & 15;
  const int bbase = blockIdx.x * 16;

  // zero Hb + Xb
  {
    float* p = (float*)&Hb[0][0][0][0];
    for (int i = tid; i < (int)(NL * 2 * 16 * HPAD / 2); i += 256) p[i] = 0.0f;
    float* px = (float*)&Xb[0][0][0];
    for (int i = tid; i < (int)(2 * 16 * HPAD / 2); i += 256) px[i] = 0.0f;
  }
  if (tid < 96) {
    const int m = tid / NIN, i = tid - m * NIN;
    Xb[0][m][i] = (_Float16)X[((size_t)0 * BATCH + bbase + m) * NIN + i];
  }

  // ======================= ENCODER: wavefront pipeline =====================
  h8 we[16][4];
  #pragma unroll
  for (int nt = 0; nt < 16; nt++)
    #pragma unroll
    for (int kt = 0; kt < 4; kt++)
      we[nt][kt] = WQ[(PACK_H8 + PROJ_H8) + ((wv * 64 + nt * 4 + kt) * 64 + lane)];

  float ben[16];
  #pragma unroll
  for (int nt = 0; nt < 16; nt++) ben[nt] = encb[wv * 256 + nt * 16 + r16];

  f32x4 ce[4];
  #pragma unroll
  for (int ct = 0; ct < 4; ct++) ce[ct] = SPLAT(0.f);

  // 2-deep X prefetch pipeline (wave 0, lanes 0..47: 2 floats each)
  const bool pfLane = (wv == 0) && (lane < 48);
  const int pe0 = lane * 2, pe1 = pe0 + 1;
  const int pm0 = pe0 / NIN, pc0 = pe0 % NIN;
  const int pm1 = pe1 / NIN, pc1 = pe1 % NIN;
  float pf0 = 0.f, pf1 = 0.f;
  if (pfLane) {            // t = 1
    const float* xs = X + ((size_t)1 * BATCH + bbase) * NIN;
    pf0 = xs[pe0]; pf1 = xs[pe1];
  }

  __syncthreads();

  #pragma unroll 1
  for (int i = 0; i < S_LEN + NL - 1; i++) {     // 123 intervals
    const int p = i & 1;
    const bool active = (i >= wv) && (i - wv < S_LEN);
    if (active) {
      const _Float16* inb = (wv == 0) ? &Xb[p][0][0] : &Hb[wv - 1][p ^ 1][0][0];
      const _Float16* rcb = &Hb[wv][p ^ 1][0][0];
      h8 ai0 = *(const h8*)(inb + r16 * HPAD + quad * 8);
      h8 ai1 = *(const h8*)(inb + r16 * HPAD + 32 + quad * 8);
      h8 ar0 = *(const h8*)(rcb + r16 * HPAD + quad * 8);
      h8 ar1 = *(const h8*)(rcb + r16 * HPAD + 32 + quad * 8);

      // issue prefetch for t = i+2 (consumed two intervals later)
      float nf0 = 0.f, nf1 = 0.f;
      if (pfLane && (i + 2 < S_LEN)) {
        const float* xs = X + ((size_t)(i + 2) * BATCH + bbase) * NIN;
        nf0 = xs[pe0]; nf1 = xs[pe1];
      }

      f32x4 acc[16];
      #pragma unroll
      for (int nt = 0; nt < 16; nt++) {
        f32x4 a = SPLAT(ben[nt]);
        a = mf(ai0, we[nt][0], a);
        a = mf(ai1, we[nt][1], a);
        a = mf(ar0, we[nt][2], a);
        a = mf(ar1, we[nt][3], a);
        acc[nt] = a;
      }

      _Float16* wb = &Hb[wv][p][0][0];
      #pragma unroll
      for (int r = 0; r < 4; r++) {
        h4 hv;
        #pragma unroll
        for (int ct = 0; ct < 4; ct++) {
          float cv = ce[ct][r];
          hv[ct] = (_Float16)ew_one(acc[ct][r], acc[4 + ct][r],
                                    acc[8 + ct][r], acc[12 + ct][r], cv);
          ce[ct][r] = cv;
        }
        *(h4*)(wb + (quad * 4 + r) * HPAD + 4 * r16) = hv;   // permuted write
      }

      // write x[t=i+1] (loaded one interval ago) into Xb[(i+1)&1]
      if (pfLane && (i + 1 < S_LEN)) {
        Xb[p ^ 1][pm0][pc0] = (_Float16)pf0;
        Xb[p ^ 1][pm1][pc1] = (_Float16)pf1;
      }
      pf0 = nf0; pf1 = nf1;
    }
    bar_lgkm();
  }

  // ===================== transition: encoder -> decoder ====================
  #pragma unroll
  for (int ct = 0; ct < 4; ct++)
    #pragma unroll
    for (int r = 0; r < 4; r++)
      Cx[wv][quad * 4 + r][ct * 16 + r16] = ce[ct][r];

  // unpermute final h of each layer into Hb[l][1] (plain layout)
  float hreg[16];
  #pragma unroll
  for (int u = 0; u < 16; u++) {
    int i2 = tid + u * 256;
    int l = i2 >> 10, m = (i2 >> 6) & 15, c = i2 & 63;
    hreg[u] = (float)Hb[l][(l + 1) & 1][m][PI(c)];
  }
  __syncthreads();
  #pragma unroll
  for (int u = 0; u < 16; u++) {
    int i2 = tid + u * 256;
    int l = i2 >> 10, m = (i2 >> 6) & 15, c = i2 & 63;
    Hb[l][1][m][c] = (_Float16)hreg[u];
  }
  __syncthreads();

  // decoder c-state slices
  f32x4 cs0, cs1, cs2, cs3;
  #pragma unroll
  for (int r = 0; r < 4; r++) {
    cs0[r] = Cx[0][quad * 4 + r][wv * 16 + r16];
    cs1[r] = Cx[1][quad * 4 + r][wv * 16 + r16];
    cs2[r] = Cx[2][quad * 4 + r][wv * 16 + r16];
    cs3[r] = Cx[3][quad * 4 + r][wv * 16 + r16];
  }

  // decoder weights (col-sliced, dec half) + biases
  h8 w0[12], w1[16], w2[16], w3[16];
  #pragma unroll
  for (int f = 0; f < 12; f++) w0[f] = WQ[((FRAGS_HALF + f)      * 4 + wv) * 64 + lane];
  #pragma unroll
  for (int f = 0; f < 16; f++) w1[f] = WQ[((FRAGS_HALF + 12 + f) * 4 + wv) * 64 + lane];
  #pragma unroll
  for (int f = 0; f < 16; f++) w2[f] = WQ[((FRAGS_HALF + 28 + f) * 4 + wv) * 64 + lane];
  #pragma unroll
  for (int f = 0; f < 16; f++) w3[f] = WQ[((FRAGS_HALF + 44 + f) * 4 + wv) * 64 + lane];

  f32x4 b0, b1, b2, b3;
  #pragma unroll
  for (int q = 0; q < 4; q++) {
    b0[q] = decb[0 * 256 + q * 64 + wv * 16 + r16];
    b1[q] = decb[1 * 256 + q * 64 + wv * 16 + r16];
    b2[q] = decb[2 * 256 + q * 64 + wv * 16 + r16];
    b3[q] = decb[3 * 256 + q * 64 + wv * 16 + r16];
  }

  h8 lwA0 = WQ[PACK_H8 + lane];
  h8 lwA1 = WQ[PACK_H8 + 64 + lane];
  f32x4 lbq;
  #pragma unroll
  for (int r = 0; r < 4; r++)
    lbq[r] = (quad * 4 + r < NIN) ? linb[quad * 4 + r] : 0.0f;

  // seed accumulators from encoder-final h (ac3 comes from interval A)
  f32x4 ac0[4], ac1[4], ac2[4], ac3[4];
  {
    h8 s0, s1;
    readA(&Hb[0][1][0][0], r16, quad, s0, s1); prec0(w0, s0, s1, b0, ac0);
    readA(&Hb[1][1][0][0], r16, quad, s0, s1); precH(w1, s0, s1, b1, ac1);
    readA(&Hb[2][1][0][0], r16, quad, s0, s1); precH(w2, s0, s1, b2, ac2);
  }
  __syncthreads();

  // ============================== DECODER ================================
  #pragma unroll 1
  for (int t = 0; t < TLEN; t++) {
    const int cur = t & 1, prv = cur ^ 1;
    // ---- interval A: proj(h3[t-1]) + layer-0 fire + acc3 precompute ----
    {
      h8 ar0, ar1;
      readA(&Hb[3][prv][0][0], r16, quad, ar0, ar1);
      h8 ax;
      if (t == 0) {
        ax = *(const h8*)(&Xb[1][0][0] + r16 * HPAD + quad * 8);  // x[119]
      } else {
        f32x4 ap = lbq;
        ap = mf(lwA0, ar0, ap);     // A = linW (m=feature), B = h3 (n=batch)
        ap = mf(lwA1, ar1, ap);
        if (wv == 0) {
          #pragma unroll
          for (int r = 0; r < 4; r++) {
            const int fm = quad * 4 + r;
            if (fm < NIN)
              out[((size_t)(t - 1) * BATCH + bbase + r16) * NIN + fm] = ap[r];
          }
        }
        // transpose (feature,batch)->(batch,feature); batch = lane&15
        float x0 = __shfl(ap[0], r16);
        float x1 = __shfl(ap[1], r16);
        float x2 = __shfl(ap[2], r16);
        float x3 = __shfl(ap[3], r16);
        float x4 = __shfl(ap[0], 16 + r16);
        float x5 = __shfl(ap[1], 16 + r16);
        h8 xa = {};
        xa[0] = (_Float16)x0; xa[1] = (_Float16)x1; xa[2] = (_Float16)x2;
        xa[3] = (_Float16)x3; xa[4] = (_Float16)x4; xa[5] = (_Float16)x5;
        h8 zz = {};
        ax = (quad == 0) ? xa : zz;
      }
      precH(w3, ar0, ar1, b3, ac3);
      fire0(w0, ax, ac0, cs0, &Hb[0][cur][0][0], quad, r16, wv);
      bar_lgkm();
    }
    // ---- interval B ----
    {
      h8 ai0, ai1;
      readA(&Hb[0][cur][0][0], r16, quad, ai0, ai1);
      fireH(w1, ai0, ai1, ac1, cs1, &Hb[1][cur][0][0], quad, r16, wv);
      prec0(w0, ai0, ai1, b0, ac0);
      bar_lgkm();
    }
    // ---- interval C ----
    {
      h8 ai0, ai1;
      readA(&Hb[1][cur][0][0], r16, quad, ai0, ai1);
      fireH(w2, ai0, ai1, ac2, cs2, &Hb[2][cur][0][0], quad, r16, wv);
      precH(w1, ai0, ai1, b1, ac1);
      bar_lgkm();
    }
    // ---- interval D ----
    {
      h8 ai0, ai1;
      readA(&Hb[2][cur][0][0], r16, quad, ai0, ai1);
      fireH(w3, ai0, ai1, ac3, cs3, &Hb[3][cur][0][0], quad, r16, wv);
      precH(w2, ai0, ai1, b2, ac2);
      bar_lgkm();
    }
  }

  // epilogue: out[TLEN-1] from h3 of last step (parity 1)
  if (wv == 0) {
    h8 ar0, ar1;
    readA(&Hb[3][1][0][0], r16, quad, ar0, ar1);
    f32x4 ap = lbq;
    ap = mf(lwA0, ar0, ap);
    ap = mf(lwA1, ar1, ap);
    #pragma unroll
    for (int r = 0; r < 4; r++) {
      const int fm = quad * 4 + r;
      if (fm < NIN)
        out[((size_t)(TLEN - 1) * BATCH + bbase + r16) * NIN + fm] = ap[r];
    }
  }
}

// ---------------------------------------------------------------------------
extern "C" void kernel_launch(void* const* d_in, const int* in_sizes, int n_in,
                              void* d_out, int out_size, void* d_ws, size_t ws_size,
                              hipStream_t stream) {
  const float* X     = (const float*)d_in[0];
  const float* eWih0 = (const float*)d_in[1];
  const float* eWih  = (const float*)d_in[2];
  const float* eWhh  = (const float*)d_in[3];
  const float* eb    = (const float*)d_in[4];
  const float* dWih0 = (const float*)d_in[5];
  const float* dWih  = (const float*)d_in[6];
  const float* dWhh  = (const float*)d_in[7];
  const float* db    = (const float*)d_in[8];
  const float* lW    = (const float*)d_in[9];
  const float* lb    = (const float*)d_in[10];

  _Float16* wq = (_Float16*)d_ws;

  prep_weights<<<(NTOT + 255) / 256, 256, 0, stream>>>(
      eWih0, eWih, eWhh, dWih0, dWih, dWhh, lW, wq);

  lstm_main<<<BATCH / 16, 256, 0, stream>>>(
      X, eb, db, lb, (const h8*)wq, (float*)d_out);
}